// Round 1
// baseline (9.728 us; speedup 1.0000x reference)
//
#include <hip/hip_runtime.h>
#include <math.h>

// Reference: out[b][h] = h_init[h] scanned through 4096 sequential "*= foo"
// steps. x is never used by the scan body. B=8, T=4096, H=4096.
//
// Key semantics: the reference multiplies step-by-step, so h_init==0 stays
// exactly 0 even when foo^4096 would overflow (0*foo == 0 each step, whereas
// 0*inf == NaN). Therefore we must NOT precompute foo^T; instead we run the
// serial chain, with the mathematically-exact absorbing-state early exit:
// if v == 0 and foo is finite, v remains 0 for all remaining steps.

#define B_DIM 8
#define T_STEPS 4096
#define H_DIM 4096

__global__ void scan_scalar_mul_kernel(const float* __restrict__ foo,
                                       const float* __restrict__ h_init,
                                       float* __restrict__ out) {
    int idx = blockIdx.x * blockDim.x + threadIdx.x;
    if (idx >= B_DIM * H_DIM) return;

    const float f = foo[0];
    float v = h_init[idx & (H_DIM - 1)];  // h_init is (1, H), broadcast over B

    // Absorbing state: 0 * finite == 0 for every remaining step.
    if (isfinite(f) && v == 0.0f) {
        out[idx] = v;  // preserves signed zero / exact reference value
        return;
    }

    // General path: bit-exact serial multiply chain, matching the reference's
    // rounding order ( ((h*f)*f)*f ... ). Dependent chain ~4096 muls ≈ 7 µs.
    #pragma unroll 16
    for (int t = 0; t < T_STEPS; ++t) {
        v *= f;
    }
    out[idx] = v;
}

extern "C" void kernel_launch(void* const* d_in, const int* in_sizes, int n_in,
                              void* d_out, int out_size, void* d_ws, size_t ws_size,
                              hipStream_t stream) {
    // Inputs in setup_inputs() order: d_in[0] = x (unused by the scan),
    // d_in[1] = foo (1 element), d_in[2] = h_init (H floats).
    const float* foo    = (const float*)d_in[1];
    const float* h_init = (const float*)d_in[2];
    float* out          = (float*)d_out;  // (B, H) float32

    const int n = B_DIM * H_DIM;  // 32768 output elements
    const int block = 256;
    const int grid = (n + block - 1) / block;  // 128 blocks
    scan_scalar_mul_kernel<<<grid, block, 0, stream>>>(foo, h_init, out);
}

// Round 2
// 9.394 us; speedup vs baseline: 1.0356x; 1.0356x over previous
//
#include <hip/hip_runtime.h>
#include <math.h>

// Reference: out[b][h] = h_init[h] scanned through 4096 sequential "*= foo"
// steps; x is never read by the scan body. B=8, T=4096, H=4096.
//
// Semantics note: must NOT precompute foo^T (overflow -> inf, then 0*inf=NaN,
// while the reference's step-by-step 0*foo chain stays exactly 0). We run the
// serial chain with the exact absorbing-state shortcut: v==0 and finite foo
// stays 0 forever.
//
// This version vectorizes the fast path to float4 (one 16B store/thread,
// 8192 threads, 32 blocks) to probe whether any of the 9.7us is kernel-side;
// prediction: it's launch-overhead floor, duration unchanged.

#define B_DIM 8
#define T_STEPS 4096
#define H_DIM 4096

__global__ void scan_scalar_mul_kernel(const float* __restrict__ foo,
                                       const float* __restrict__ h_init,
                                       float* __restrict__ out) {
    int idx = blockIdx.x * blockDim.x + threadIdx.x;   // vec4 index
    const int nvec = (B_DIM * H_DIM) / 4;              // 8192
    if (idx >= nvec) return;

    const float f = foo[0];
    const int hvec = idx & ((H_DIM / 4) - 1);          // h_init broadcast over B

    float4 v = reinterpret_cast<const float4*>(h_init)[hvec];

    // Absorbing state: 0 * finite == 0 for every remaining step.
    if (isfinite(f) && v.x == 0.0f && v.y == 0.0f && v.z == 0.0f && v.w == 0.0f) {
        reinterpret_cast<float4*>(out)[idx] = v;       // bit-exact (signed zeros preserved)
        return;
    }

    // General path: 4 independent serial chains, same rounding order as the
    // reference ( ((h*f)*f)*f ... ). ~4096 dependent muls, 4-wide ILP.
    #pragma unroll 16
    for (int t = 0; t < T_STEPS; ++t) {
        v.x *= f; v.y *= f; v.z *= f; v.w *= f;
    }
    reinterpret_cast<float4*>(out)[idx] = v;
}

extern "C" void kernel_launch(void* const* d_in, const int* in_sizes, int n_in,
                              void* d_out, int out_size, void* d_ws, size_t ws_size,
                              hipStream_t stream) {
    // setup_inputs() order: d_in[0] = x (unused), d_in[1] = foo, d_in[2] = h_init.
    const float* foo    = (const float*)d_in[1];
    const float* h_init = (const float*)d_in[2];
    float* out          = (float*)d_out;               // (B, H) float32

    const int nvec = (B_DIM * H_DIM) / 4;              // 8192 float4 stores
    const int block = 256;
    const int grid = (nvec + block - 1) / block;       // 32 blocks
    scan_scalar_mul_kernel<<<grid, block, 0, stream>>>(foo, h_init, out);
}